// Round 9
// baseline (370.326 us; speedup 1.0000x reference)
//
#include <hip/hip_runtime.h>
#include <hip/hip_bf16.h>
#include <stdint.h>

typedef _Float16 f16x8 __attribute__((ext_vector_type(8)));
typedef _Float16 f16x4 __attribute__((ext_vector_type(4)));
typedef _Float16 f16x2 __attribute__((ext_vector_type(2)));
typedef float    f32x4 __attribute__((ext_vector_type(4)));

#define NPROTO 1024
#define EMB    512
#define NB     16
#define HW     4096           // 64*64
#define NPIX   (NB * HW)      // 65536
#define INV_TEMP 10.0f        // 1/0.1

// ---------------- prep: prototypes f32 -> fp16, pnorm = |p|^2 (exact f32) ----------------
__global__ void prep_protos(const float* __restrict__ proto,
                            _Float16* __restrict__ Ph,
                            float* __restrict__ pnorm) {
    int k = blockIdx.x;          // 1024 blocks, 1 wave each
    int t = threadIdx.x;
    const float* src = proto + (size_t)k * EMB + t * 8;
    float4 v0 = ((const float4*)src)[0];
    float4 v1 = ((const float4*)src)[1];
    float sq = v0.x*v0.x + v0.y*v0.y + v0.z*v0.z + v0.w*v0.w
             + v1.x*v1.x + v1.y*v1.y + v1.z*v1.z + v1.w*v1.w;
    f16x8 h;
    h[0] = (_Float16)v0.x; h[1] = (_Float16)v0.y; h[2] = (_Float16)v0.z; h[3] = (_Float16)v0.w;
    h[4] = (_Float16)v1.x; h[5] = (_Float16)v1.y; h[6] = (_Float16)v1.z; h[7] = (_Float16)v1.w;
    *(f16x8*)(Ph + (size_t)k * EMB + t * 8) = h;
#pragma unroll
    for (int m = 1; m < 64; m <<= 1) sq += __shfl_xor(sq, m);
    if (t == 0) pnorm[k] = sq;
}

__global__ void zero_counts(int* __restrict__ counts) {
    int i = blockIdx.x * blockDim.x + threadIdx.x;
    if (i < NB * NPROTO) counts[i] = 0;
}

// ================= p0: fm [b][c][px] f32 -> Xh [b][px][c] fp16 (+ exact xn) ===============
__global__ __launch_bounds__(1024)
void p0_transpose(const float* __restrict__ fm, _Float16* __restrict__ Xh,
                  float* __restrict__ xn) {
    __shared__ __align__(16) unsigned char tile[128 * 1024];   // 128 px rows x 1KB (512 f16)
    __shared__ float xnpart[32 * 128];                         // 16 KB

    const int t   = threadIdx.x;
    const int b   = blockIdx.x >> 5;          // 32 px-tiles per image
    const int px0 = (blockIdx.x & 31) * 128;

    float sq0 = 0.f, sq1 = 0.f, sq2 = 0.f, sq3 = 0.f;
    const int p4 = t & 31;                    // fixed float4 column for this thread
#pragma unroll
    for (int j = 0; j < 16; ++j) {
        int f4 = j * 1024 + t;
        int c  = f4 >> 5;                     // [0,512)
        float4 v = *(const float4*)(fm + ((size_t)b * EMB + c) * HW + px0 + p4 * 4);
        sq0 += v.x * v.x; sq1 += v.y * v.y; sq2 += v.z * v.z; sq3 += v.w * v.w;
#pragma unroll
        for (int i = 0; i < 4; ++i) {
            int p = p4 * 4 + i;
            float val = (i == 0) ? v.x : (i == 1) ? v.y : (i == 2) ? v.z : v.w;
            int slot = (c >> 3) ^ ((p >> 2) & 63);
            *(_Float16*)(tile + p * 1024 + slot * 16 + (c & 7) * 2) = (_Float16)val;
        }
    }
    xnpart[(t >> 5) * 128 + p4 * 4 + 0] = sq0;
    xnpart[(t >> 5) * 128 + p4 * 4 + 1] = sq1;
    xnpart[(t >> 5) * 128 + p4 * 4 + 2] = sq2;
    xnpart[(t >> 5) * 128 + p4 * 4 + 3] = sq3;
    __syncthreads();

    if (t < 128) {
        float s = 0.f;
#pragma unroll
        for (int g = 0; g < 32; ++g) s += xnpart[g * 128 + t];
        xn[b * HW + px0 + t] = s;
    }
    const int wid = t >> 6, lane = t & 63;
#pragma unroll
    for (int rr = 0; rr < 8; ++rr) {
        int p = wid * 8 + rr;
        int phys = lane ^ ((p >> 2) & 63);
        f16x8 v = *(const f16x8*)(tile + p * 1024 + phys * 16);
        *(f16x8*)(Xh + ((size_t)b * HW + px0 + p) * EMB + lane * 8) = v;
    }
}

// ================= pA v4: 256k x 256px, BK=64, 4-phase interleaved schedule ================
// grid = 256 px-tiles x 4 slices (slice-outer). 512 thr = 8 waves (2 kw x 4 pw);
// wave = 128k x 64px, acc[8][4] f32x4. LDS: 2 bufs x (A 32K + B 32K) = 128 KB, 1 blk/CU.
// Per K-tile: 4 phases, each {stage 1 half-tile of t+1 (2 gload_lds) | ds_reads | bar |
// setprio(1) 16 MFMA setprio(0) | bar}; one __syncthreads (vmcnt drain) per tile boundary.
// Swizzle: 16B slot s holds c-group s ^ (row&7); inverse pre-applied on global source.
__global__ __launch_bounds__(512, 2)
void pA_gemm(const _Float16* __restrict__ Xh, const _Float16* __restrict__ Ph,
             const float* __restrict__ pnorm, const float* __restrict__ xn,
             _Float16* __restrict__ e_out, float4* __restrict__ pstat) {
    __shared__ __align__(16) unsigned char smem[132096];   // 2x64K bufs + 1K pn
    float* pn = (float*)(smem + 131072);       // 256 f32, live whole kernel
    // epilogue aliases into dead buf0:
    float* redsum = (float*)(smem + 2048);     // [2 kw][256 px]
    float* argv_  = (float*)(smem + 4096);     // [2 kw][256 px] (value == max)
    int*   argk_  = (int*)(smem + 6144);

    const int t    = threadIdx.x;
    const int lane = t & 63, wid = t >> 6;
    const int kw   = wid >> 2, pw = wid & 3;   // 2 kw x 4 pw
    const int lrow = lane >> 4, lcol = lane & 15;

    const int pt    = blockIdx.x & 255, slice = blockIdx.x >> 8;
    const int gpx0  = pt * 256;
    const int k0g   = slice * 256;

    if (t < 256) pn[t] = pnorm[k0g + t];

    f32x4 acc[8][4];
#pragma unroll
    for (int i = 0; i < 8; ++i)
#pragma unroll
        for (int j = 0; j < 4; ++j)
#pragma unroll
            for (int e = 0; e < 4; ++e) acc[i][j][e] = 0.0f;

    // staging: 512 thr cover 64 rows x 8 slots per round; 2 rounds per half-tile (128 rows)
    const int srow8 = t >> 3, sslot = t & 7;
    auto stage_half = [&](int buf, int kt, int half) {
#pragma unroll
        for (int r2 = 0; r2 < 2; ++r2) {
            int row = (half & 1) * 128 + r2 * 64 + srow8;
            int cg  = sslot ^ (row & 7);
            const _Float16* src = (half >= 2)
                ? (Xh + (size_t)(gpx0 + row) * EMB + kt * 64 + cg * 8)
                : (Ph + (size_t)(k0g + row) * EMB + kt * 64 + cg * 8);
            __builtin_amdgcn_global_load_lds(
                (const __attribute__((address_space(1))) void*)src,
                (__attribute__((address_space(3))) void*)(smem + buf * 65536 +
                    ((half >= 2) ? 32768 : 0) + row * 128 + sslot * 16),
                16, 0, 0);
        }
    };

    // prologue: stage tile 0 fully into buf 0
    stage_half(0, 0, 0); stage_half(0, 0, 1); stage_half(0, 0, 2); stage_half(0, 0, 3);
    __syncthreads();

    // per-thread ds_read constants: slot = (kk*4+lrow) ^ (lcol&7)
    const int swz0 = ((lrow)     ^ (lcol & 7)) << 4;   // kk=0
    const int swz1 = ((4 + lrow) ^ (lcol & 7)) << 4;   // kk=1
    const int aoff = (kw * 128 + lcol) * 128;           // + mf*2048
    const int boff = 32768 + (pw * 64 + lcol) * 128;    // + nf*2048

#pragma unroll 2
    for (int kt = 0; kt < 8; ++kt) {
        const unsigned char* cb = smem + (kt & 1) * 65536;
        const int nbuf = (kt & 1) ^ 1;
        f16x8 afr[4][2], bfr[4][2];

        // ---- phase 0: stage A-half0(t+1); read all bf + af(mf0-3); MFMA mf0-3 x nf0-1 ----
        if (kt < 7) stage_half(nbuf, kt + 1, 0);
#pragma unroll
        for (int nf = 0; nf < 4; ++nf) {
            bfr[nf][0] = *(const f16x8*)(cb + boff + nf * 2048 + swz0);
            bfr[nf][1] = *(const f16x8*)(cb + boff + nf * 2048 + swz1);
        }
#pragma unroll
        for (int mf = 0; mf < 4; ++mf) {
            afr[mf][0] = *(const f16x8*)(cb + aoff + mf * 2048 + swz0);
            afr[mf][1] = *(const f16x8*)(cb + aoff + mf * 2048 + swz1);
        }
        __builtin_amdgcn_s_barrier();
        __builtin_amdgcn_s_setprio(1);
#pragma unroll
        for (int mf = 0; mf < 4; ++mf)
#pragma unroll
            for (int nf = 0; nf < 2; ++nf) {
                acc[mf][nf] = __builtin_amdgcn_mfma_f32_16x16x32_f16(afr[mf][0], bfr[nf][0], acc[mf][nf], 0, 0, 0);
                acc[mf][nf] = __builtin_amdgcn_mfma_f32_16x16x32_f16(afr[mf][1], bfr[nf][1], acc[mf][nf], 0, 0, 0);
            }
        __builtin_amdgcn_s_setprio(0);
        __builtin_amdgcn_s_barrier();

        // ---- phase 1: stage A-half1(t+1); MFMA mf0-3 x nf2-3 (reuse afr/bfr) ----
        if (kt < 7) stage_half(nbuf, kt + 1, 1);
        __builtin_amdgcn_s_setprio(1);
#pragma unroll
        for (int mf = 0; mf < 4; ++mf)
#pragma unroll
            for (int nf = 2; nf < 4; ++nf) {
                acc[mf][nf] = __builtin_amdgcn_mfma_f32_16x16x32_f16(afr[mf][0], bfr[nf][0], acc[mf][nf], 0, 0, 0);
                acc[mf][nf] = __builtin_amdgcn_mfma_f32_16x16x32_f16(afr[mf][1], bfr[nf][1], acc[mf][nf], 0, 0, 0);
            }
        __builtin_amdgcn_s_setprio(0);
        __builtin_amdgcn_s_barrier();

        // ---- phase 2: stage B-half0(t+1); read af(mf4-7); MFMA mf4-7 x nf0-1 ----
        if (kt < 7) stage_half(nbuf, kt + 1, 2);
#pragma unroll
        for (int mf = 0; mf < 4; ++mf) {
            afr[mf][0] = *(const f16x8*)(cb + aoff + (mf + 4) * 2048 + swz0);
            afr[mf][1] = *(const f16x8*)(cb + aoff + (mf + 4) * 2048 + swz1);
        }
        __builtin_amdgcn_s_barrier();
        __builtin_amdgcn_s_setprio(1);
#pragma unroll
        for (int mf = 0; mf < 4; ++mf)
#pragma unroll
            for (int nf = 0; nf < 2; ++nf) {
                acc[mf + 4][nf] = __builtin_amdgcn_mfma_f32_16x16x32_f16(afr[mf][0], bfr[nf][0], acc[mf + 4][nf], 0, 0, 0);
                acc[mf + 4][nf] = __builtin_amdgcn_mfma_f32_16x16x32_f16(afr[mf][1], bfr[nf][1], acc[mf + 4][nf], 0, 0, 0);
            }
        __builtin_amdgcn_s_setprio(0);
        __builtin_amdgcn_s_barrier();

        // ---- phase 3: stage B-half1(t+1); MFMA mf4-7 x nf2-3; tile-boundary sync ----
        if (kt < 7) stage_half(nbuf, kt + 1, 3);
        __builtin_amdgcn_s_setprio(1);
#pragma unroll
        for (int mf = 0; mf < 4; ++mf)
#pragma unroll
            for (int nf = 2; nf < 4; ++nf) {
                acc[mf + 4][nf] = __builtin_amdgcn_mfma_f32_16x16x32_f16(afr[mf][0], bfr[nf][0], acc[mf + 4][nf], 0, 0, 0);
                acc[mf + 4][nf] = __builtin_amdgcn_mfma_f32_16x16x32_f16(afr[mf][1], bfr[nf][1], acc[mf + 4][nf], 0, 0, 0);
            }
        __builtin_amdgcn_s_setprio(0);
        __syncthreads();   // drains vmcnt(0): tile t+1 staged; buf swap safe
    }

    // ---- logits; per-(kw) slice-partial max/argmax (max == argmax value, no separate lmax) ----
    float xnv[4];
#pragma unroll
    for (int nf = 0; nf < 4; ++nf) xnv[nf] = xn[gpx0 + pw * 64 + nf * 16 + lcol];

    float lav[4] = {-1e30f, -1e30f, -1e30f, -1e30f};
    int   lak[4] = {0, 0, 0, 0};
#pragma unroll
    for (int mf = 0; mf < 8; ++mf) {
        const int klb = kw * 128 + mf * 16 + lrow * 4;
        float4 pn4 = *(const float4*)(pn + klb);
#pragma unroll
        for (int nf = 0; nf < 4; ++nf)
#pragma unroll
            for (int j = 0; j < 4; ++j) {
                float pnj = (j == 0) ? pn4.x : (j == 1) ? pn4.y : (j == 2) ? pn4.z : pn4.w;
                float d2 = fmaxf(xnv[nf] + pnj - 2.0f * acc[mf][nf][j], 0.0f);
                float sq;
                asm("v_sqrt_f32 %0, %1" : "=v"(sq) : "v"(d2));
                float lg = -INV_TEMP * sq;
                acc[mf][nf][j] = lg;
                if (lg > lav[nf]) { lav[nf] = lg; lak[nf] = klb + j; }   // ascending k, strict >
            }
    }
#pragma unroll
    for (int nf = 0; nf < 4; ++nf)
#pragma unroll
        for (int m = 16; m <= 32; m <<= 1) {
            float ov = __shfl_xor(lav[nf], m);
            int   ok = __shfl_xor(lak[nf], m);
            if (ov > lav[nf] || (ov == lav[nf] && ok < lak[nf])) { lav[nf] = ov; lak[nf] = ok; }
        }
    if (lane < 16)
#pragma unroll
        for (int nf = 0; nf < 4; ++nf) {
            int px = pw * 64 + nf * 16 + lane;
            argv_[kw * 256 + px] = lav[nf];
            argk_[kw * 256 + px] = lak[nf];
        }
    __syncthreads();

    // ---- slice max per px (= max of 2 kw argmax values); e = exp(lg - m); partial sums ----
#pragma unroll
    for (int nf = 0; nf < 4; ++nf) {
        int px = pw * 64 + nf * 16 + lcol;
        float m = fmaxf(argv_[px], argv_[256 + px]);
        float s = 0.0f;
#pragma unroll
        for (int mf = 0; mf < 8; ++mf)
#pragma unroll
            for (int j = 0; j < 4; ++j) {
                float e = __expf(acc[mf][nf][j] - m);
                acc[mf][nf][j] = e;
                s += e;
            }
        s += __shfl_xor(s, 16);
        s += __shfl_xor(s, 32);
        if (lane < 16) redsum[kw * 256 + nf * 16 + pw * 64 + lane] = s;
    }

    // ---- write e (fp16) px-contiguous: e[gpx][k0g + kl] ----
#pragma unroll
    for (int mf = 0; mf < 8; ++mf)
#pragma unroll
        for (int nf = 0; nf < 4; ++nf) {
            int px = pw * 64 + nf * 16 + lcol;
            int kl = kw * 128 + mf * 16 + lrow * 4;
            f16x4 h;
#pragma unroll
            for (int j = 0; j < 4; ++j) h[j] = (_Float16)acc[mf][nf][j];
            *(f16x4*)(e_out + (size_t)(gpx0 + px) * NPROTO + k0g + kl) = h;
        }
    __syncthreads();

    // ---- per-px slice stats: {pmax, psum, argmax k (global)} ----
    if (kw == 0 && lane < 16) {
#pragma unroll
        for (int nf = 0; nf < 4; ++nf) {
            int px = pw * 64 + nf * 16 + lane;
            float av = argv_[px]; int ak = argk_[px];
            float a1 = argv_[256 + px]; int k1 = argk_[256 + px];
            if (a1 > av) { av = a1; ak = k1; }      // kw0 first -> ties keep smaller k
            float s = redsum[px] + redsum[256 + px];
            float4 st;
            st.x = av; st.y = s; st.z = __int_as_float(k0g + ak); st.w = 0.0f;
            pstat[(size_t)slice * NPIX + gpx0 + px] = st;
        }
    }
}

// ================= pC: combine 4 slice stats -> per-slice scale, argmax counts =============
__global__ void pC_combine(const float4* __restrict__ pstat, float* __restrict__ scale,
                           int* __restrict__ counts) {
    int px = blockIdx.x * 256 + threadIdx.x;
    if (px >= NPIX) return;
    float4 s0 = pstat[px];
    float4 s1 = pstat[NPIX + px];
    float4 s2 = pstat[2 * NPIX + px];
    float4 s3 = pstat[3 * NPIX + px];
    float m = fmaxf(fmaxf(s0.x, s1.x), fmaxf(s2.x, s3.x));
    float e0 = __expf(s0.x - m), e1 = __expf(s1.x - m);
    float e2 = __expf(s2.x - m), e3 = __expf(s3.x - m);
    float S = s0.y * e0 + s1.y * e1 + s2.y * e2 + s3.y * e3;
    float rs = 1.0f / S;
    scale[px * 4 + 0] = e0 * rs;
    scale[px * 4 + 1] = e1 * rs;
    scale[px * 4 + 2] = e2 * rs;
    scale[px * 4 + 3] = e3 * rs;
    float bv = s0.x; int bk = __float_as_int(s0.z);
    if (s1.x > bv) { bv = s1.x; bk = __float_as_int(s1.z); }
    if (s2.x > bv) { bv = s2.x; bk = __float_as_int(s2.z); }
    if (s3.x > bv) { bv = s3.x; bk = __float_as_int(s3.z); }
    int b = px >> 12;
    atomicAdd(&counts[b * NPROTO + bk], 1);
}

// ================= pB: transpose+scale stream: out[b][k][px] = e[px][k] * scale ============
__global__ __launch_bounds__(1024)
void pB_emit(const _Float16* __restrict__ e, const float* __restrict__ scale,
             float* __restrict__ out) {
    __shared__ float tile[64 * 261];            // [k][px], pad -> mild conflicts only

    const int t = threadIdx.x;
    const int px0g = blockIdx.x * 256;
    const int b = px0g >> 12, hw0 = px0g & 4095;
    const int lpx = t >> 2, kq = t & 3;         // load: 256 px x 4 k-quads (16 f16 each)
    const int orow = t >> 4, oseg = t & 15;     // store: 64 rows x 16 segs

    for (int kc = 0; kc < 16; ++kc) {
        int slice = kc >> 2;
        float sc = scale[(px0g + lpx) * 4 + slice];
        const _Float16* src = e + (size_t)(px0g + lpx) * NPROTO + kc * 64 + kq * 16;
        f16x8 h0 = *(const f16x8*)(src);
        f16x8 h1 = *(const f16x8*)(src + 8);
        if (kc) __syncthreads();                 // prev chunk's readers done
#pragma unroll
        for (int j = 0; j < 8; ++j) {
            tile[(kq * 16 + j) * 261 + lpx]     = (float)h0[j] * sc;
            tile[(kq * 16 + 8 + j) * 261 + lpx] = (float)h1[j] * sc;
        }
        __syncthreads();
        size_t obase = (size_t)b * NPROTO * HW + (size_t)(kc * 64 + orow) * HW + hw0 + oseg * 16;
#pragma unroll
        for (int i = 0; i < 4; ++i) {
            float4 v;
            v.x = tile[orow * 261 + oseg * 16 + i * 4 + 0];
            v.y = tile[orow * 261 + oseg * 16 + i * 4 + 1];
            v.z = tile[orow * 261 + oseg * 16 + i * 4 + 2];
            v.w = tile[orow * 261 + oseg * 16 + i * 4 + 3];
            *(float4*)(out + obase + i * 4) = v;
        }
    }
}

// ---------------- finalize: mask = (counts > 3).sum() / 16 ----------------
__global__ void finalize(const int* __restrict__ counts, float* __restrict__ out) {
    int t = threadIdx.x;  // 256
    int local = 0;
    for (int i = t; i < NB * NPROTO; i += 256) local += (counts[i] > 3) ? 1 : 0;
#pragma unroll
    for (int m = 1; m < 64; m <<= 1) local += __shfl_xor(local, m);
    __shared__ int wsum[4];
    if ((t & 63) == 0) wsum[t >> 6] = local;
    __syncthreads();
    if (t == 0) out[(size_t)NPIX * NPROTO] = (float)(wsum[0] + wsum[1] + wsum[2] + wsum[3]) / 16.0f;
}

// ================= fallback (validated round-3 fused kernel, used if ws too small) ========
__global__ __launch_bounds__(1024, 1)
void assign_fused(const float* __restrict__ fm, const _Float16* __restrict__ Ph,
                  const float* __restrict__ pnorm, int* __restrict__ counts,
                  float* __restrict__ out) {
    __shared__ __align__(16) unsigned char smem[143360];
    unsigned char* Abuf = smem;
    unsigned char* Bbuf = smem + 131072;
    float* pn           = (float*)(smem + 139264);
    float* redmax = (float*)(smem);
    float* redsum = (float*)(smem + 4096);
    float* argv_  = (float*)(smem + 8192);
    int*   argk_  = (int*)  (smem + 12288);
    float* xnsum  = (float*)(smem + 16384);
    float* xn     = (float*)(smem + 20480);

    const int t    = threadIdx.x;
    const int lane = t & 63, wid = t >> 6;
    const int lrow = lane >> 4, lcol = lane & 15;
    const int n0  = blockIdx.x * 64;
    const int b   = n0 >> 12;
    const int hw0 = n0 & 4095;

    pn[t] = pnorm[t];
    f32x4 acc[4][4];
#pragma unroll
    for (int i = 0; i < 4; ++i)
#pragma unroll
        for (int j = 0; j < 4; ++j)
#pragma unroll
            for (int e = 0; e < 4; ++e) acc[i][j][e] = 0.0f;

    const int bpx = t & 63;
    const int bc  = (t >> 6) << 1;
    const float* fmB = fm + (size_t)b * EMB * HW + hw0 + bpx;
    float sq = 0.0f;
    float bv0, bv1;

    auto stageA = [&](int cur, int ks) {
        const int c0 = ks * 32;
#pragma unroll
        for (int p = 0; p < 4; ++p) {
            int k  = p * 256 + wid * 16 + (lane >> 2);
            int cg = (lane & 3) ^ (k & 3);
            __builtin_amdgcn_global_load_lds(
                (const __attribute__((address_space(1))) void*)(Ph + (size_t)k * EMB + c0 + cg * 8),
                (__attribute__((address_space(3))) void*)(Abuf + cur * 65536 + p * 16384 + wid * 1024),
                16, 0, 0);
        }
    };
    auto loadB = [&](int ks) {
        const float* p0 = fmB + (size_t)(ks * 32 + bc) * HW;
        bv0 = p0[0]; bv1 = p0[HW];
    };
    auto writeB = [&](int cur) {
        sq += bv0 * bv0 + bv1 * bv1;
        f16x2 h; h[0] = (_Float16)bv0; h[1] = (_Float16)bv1;
        int slot = (bc >> 3) ^ (bpx & 3);
        *(f16x2*)(Bbuf + cur * 4096 + bpx * 64 + (slot << 4) + (bc & 7) * 2) = h;
    };

    stageA(0, 0); loadB(0); writeB(0);
    __syncthreads();
    int cur = 0;
    for (int ks = 0; ks < 16; ++ks) {
        if (ks < 15) { stageA(cur ^ 1, ks + 1); loadB(ks + 1); }
        f16x8 bf[4];
#pragma unroll
        for (int nf = 0; nf < 4; ++nf) {
            int px = nf * 16 + lcol;
            bf[nf] = *(const f16x8*)(Bbuf + cur * 4096 + px * 64 + ((lrow ^ (px & 3)) << 4));
        }
#pragma unroll
        for (int mf = 0; mf < 4; ++mf) {
            int r = wid * 64 + mf * 16 + lcol;
            f16x8 af = *(const f16x8*)(Abuf + cur * 65536 + r * 64 + ((lrow ^ (r & 3)) << 4));
#pragma unroll
            for (int nf = 0; nf < 4; ++nf)
                acc[mf][nf] = __builtin_amdgcn_mfma_f32_16x16x32_f16(af, bf[nf], acc[mf][nf], 0, 0, 0);
        }
        if (ks < 15) writeB(cur ^ 1);
        __syncthreads();
        cur ^= 1;
    }

    xnsum[(t >> 6) * 64 + bpx] = sq;
    __syncthreads();
    if (t < 64) {
        float s = 0.0f;
#pragma unroll
        for (int g = 0; g < 16; ++g) s += xnsum[g * 64 + t];
        xn[t] = s;
    }
    __syncthreads();

    float xnv[4];
#pragma unroll
    for (int nf = 0; nf < 4; ++nf) xnv[nf] = xn[nf * 16 + lcol];
    float lmax[4] = {-1e30f, -1e30f, -1e30f, -1e30f};
    float lav[4]  = {-1e30f, -1e30f, -1e30f, -1e30f};
    int   lak[4]  = {0, 0, 0, 0};
#pragma unroll
    for (int mf = 0; mf < 4; ++mf)
#pragma unroll
        for (int nf = 0; nf < 4; ++nf)
#pragma unroll
            for (int j = 0; j < 4; ++j) {
                int kidx = wid * 64 + mf * 16 + lrow * 4 + j;
                float d2 = xnv[nf] + pn[kidx] - 2.0f * acc[mf][nf][j];
                float lg = -INV_TEMP * sqrtf(fmaxf(d2, 0.0f));
                acc[mf][nf][j] = lg;
                if (lg > lav[nf]) { lav[nf] = lg; lak[nf] = kidx; }
                lmax[nf] = fmaxf(lmax[nf], lg);
            }
#pragma unroll
    for (int nf = 0; nf < 4; ++nf)
#pragma unroll
        for (int m = 16; m <= 32; m <<= 1) {
            float ov = __shfl_xor(lav[nf], m);
            int   ok = __shfl_xor(lak[nf], m);
            if (ov > lav[nf] || (ov == lav[nf] && ok < lak[nf])) { lav[nf] = ov; lak[nf] = ok; }
            lmax[nf] = fmaxf(lmax[nf], __shfl_xor(lmax[nf], m));
        }
    if (lane < 16)
#pragma unroll
        for (int nf = 0; nf < 4; ++nf) {
            int idx = wid * 64 + nf * 16 + lane;
            redmax[idx] = lmax[nf]; argv_[idx] = lav[nf]; argk_[idx] = lak[nf];
        }
    __syncthreads();

#pragma unroll
    for (int nf = 0; nf < 4; ++nf) {
        int px = nf * 16 + lcol;
        float gm = -1e30f, gav = -1e30f;
        int gak = 0;
#pragma unroll
        for (int w = 0; w < 16; ++w) {
            gm = fmaxf(gm, redmax[w * 64 + px]);
            float av = argv_[w * 64 + px];
            int   ak = argk_[w * 64 + px];
            if (av > gav || (av == gav && ak < gak)) { gav = av; gak = ak; }
        }
        if (wid == 0 && lane < 16) atomicAdd(&counts[b * NPROTO + gak], 1);
        float s = 0.0f;
#pragma unroll
        for (int mf = 0; mf < 4; ++mf)
#pragma unroll
            for (int j = 0; j < 4; ++j) {
                float e = __expf(acc[mf][nf][j] - gm);
                acc[mf][nf][j] = e;
                s += e;
            }
        s += __shfl_xor(s, 16);
        s += __shfl_xor(s, 32);
        if (lane < 16) redsum[wid * 64 + nf * 16 + lane] = s;
    }
    __syncthreads();

    const size_t obase = (size_t)b * NPROTO * HW + hw0;
#pragma unroll
    for (int nf = 0; nf < 4; ++nf) {
        int px = nf * 16 + lcol;
        float s = 0.0f;
#pragma unroll
        for (int w = 0; w < 16; ++w) s += redsum[w * 64 + px];
        float inv = 1.0f / s;
#pragma unroll
        for (int mf = 0; mf < 4; ++mf)
#pragma unroll
            for (int j = 0; j < 4; ++j) {
                int kidx = wid * 64 + mf * 16 + lrow * 4 + j;
                out[obase + (size_t)kidx * HW + px] = acc[mf][nf][j] * inv;
            }
    }
}

extern "C" void kernel_launch(void* const* d_in, const int* in_sizes, int n_in,
                              void* d_out, int out_size, void* d_ws, size_t ws_size,
                              hipStream_t stream) {
    const float* fm    = (const float*)d_in[0];   // [16][512][64][64] f32
    const float* proto = (const float*)d_in[1];   // [1][1024][512] f32
    float* out = (float*)d_out;

    char* ws = (char*)d_ws;
    // fast-path ws layout
    const size_t E_OFF  = 0;                               // 65536*1024*2 = 134217728
    const size_t XH_OFF = 134217728;                       // 65536*512*2 =  67108864
    const size_t PS_OFF = XH_OFF + 67108864;               // 4*65536*16  =   4194304
    const size_t SC_OFF = PS_OFF + 4194304;                // 65536*4*4   =   1048576
    const size_t XN_OFF = SC_OFF + 1048576;                // 65536*4     =    262144
    const size_t PH_OFF = XN_OFF + 262144;                 // 1024*512*2  =   1048576
    const size_t PN_OFF = PH_OFF + 1048576;                //                   4096
    const size_t CT_OFF = PN_OFF + 4096;                   //                  65536
    const size_t NEED   = CT_OFF + 65536;

    if (ws_size >= NEED) {
        _Float16* e     = (_Float16*)(ws + E_OFF);
        _Float16* Xh    = (_Float16*)(ws + XH_OFF);
        float4*   pstat = (float4*)(ws + PS_OFF);
        float*    scale = (float*)(ws + SC_OFF);
        float*    xn    = (float*)(ws + XN_OFF);
        _Float16* Ph    = (_Float16*)(ws + PH_OFF);
        float*    pnorm = (float*)(ws + PN_OFF);
        int*      counts= (int*)(ws + CT_OFF);

        prep_protos<<<NPROTO, 64, 0, stream>>>(proto, Ph, pnorm);
        zero_counts<<<(NB * NPROTO + 255) / 256, 256, 0, stream>>>(counts);
        p0_transpose<<<NB * 32, 1024, 0, stream>>>(fm, Xh, xn);
        pA_gemm<<<(NPIX / 256) * 4, 512, 0, stream>>>(Xh, Ph, pnorm, xn, e, pstat);
        pC_combine<<<NPIX / 256, 256, 0, stream>>>(pstat, scale, counts);
        pB_emit<<<NPIX / 256, 1024, 0, stream>>>(e, scale, out);
        finalize<<<1, 256, 0, stream>>>(counts, out);
    } else {
        // fallback: validated fused path (round-3)
        _Float16* Ph    = (_Float16*)ws;
        float*    pnorm = (float*)(ws + (size_t)NPROTO * EMB * 2);
        int*      counts= (int*)(ws + (size_t)NPROTO * EMB * 2 + 4096);
        prep_protos<<<NPROTO, 64, 0, stream>>>(proto, Ph, pnorm);
        zero_counts<<<(NB * NPROTO + 255) / 256, 256, 0, stream>>>(counts);
        assign_fused<<<NPIX / 64, 1024, 0, stream>>>(fm, Ph, pnorm, counts, out);
        finalize<<<1, 256, 0, stream>>>(counts, out);
    }
}

// Round 10
// 329.596 us; speedup vs baseline: 1.1236x; 1.1236x over previous
//
#include <hip/hip_runtime.h>
#include <hip/hip_bf16.h>
#include <stdint.h>

typedef _Float16 f16x8 __attribute__((ext_vector_type(8)));
typedef _Float16 f16x4 __attribute__((ext_vector_type(4)));
typedef _Float16 f16x2 __attribute__((ext_vector_type(2)));
typedef float    f32x4 __attribute__((ext_vector_type(4)));

#define NPROTO 1024
#define EMB    512
#define NB     16
#define HW     4096           // 64*64
#define NPIX   (NB * HW)      // 65536
#define INV_TEMP 10.0f        // 1/0.1
#define NSLICE 8              // 128 k per slice

// ---------------- prep: prototypes f32 -> fp16, pnorm = |p|^2 (exact f32) ----------------
__global__ void prep_protos(const float* __restrict__ proto,
                            _Float16* __restrict__ Ph,
                            float* __restrict__ pnorm) {
    int k = blockIdx.x;          // 1024 blocks, 1 wave each
    int t = threadIdx.x;
    const float* src = proto + (size_t)k * EMB + t * 8;
    float4 v0 = ((const float4*)src)[0];
    float4 v1 = ((const float4*)src)[1];
    float sq = v0.x*v0.x + v0.y*v0.y + v0.z*v0.z + v0.w*v0.w
             + v1.x*v1.x + v1.y*v1.y + v1.z*v1.z + v1.w*v1.w;
    f16x8 h;
    h[0] = (_Float16)v0.x; h[1] = (_Float16)v0.y; h[2] = (_Float16)v0.z; h[3] = (_Float16)v0.w;
    h[4] = (_Float16)v1.x; h[5] = (_Float16)v1.y; h[6] = (_Float16)v1.z; h[7] = (_Float16)v1.w;
    *(f16x8*)(Ph + (size_t)k * EMB + t * 8) = h;
#pragma unroll
    for (int m = 1; m < 64; m <<= 1) sq += __shfl_xor(sq, m);
    if (t == 0) pnorm[k] = sq;
}

__global__ void zero_counts(int* __restrict__ counts) {
    int i = blockIdx.x * blockDim.x + threadIdx.x;
    if (i < NB * NPROTO) counts[i] = 0;
}

// ================= p0: fm [b][c][px] f32 -> Xh [b][px][c] fp16 (+ exact xn) ===============
__global__ __launch_bounds__(1024)
void p0_transpose(const float* __restrict__ fm, _Float16* __restrict__ Xh,
                  float* __restrict__ xn) {
    __shared__ __align__(16) unsigned char tile[128 * 1024];   // 128 px rows x 1KB (512 f16)
    __shared__ float xnpart[32 * 128];                         // 16 KB

    const int t   = threadIdx.x;
    const int b   = blockIdx.x >> 5;          // 32 px-tiles per image
    const int px0 = (blockIdx.x & 31) * 128;

    float sq0 = 0.f, sq1 = 0.f, sq2 = 0.f, sq3 = 0.f;
    const int p4 = t & 31;                    // fixed float4 column for this thread
#pragma unroll
    for (int j = 0; j < 16; ++j) {
        int f4 = j * 1024 + t;
        int c  = f4 >> 5;                     // [0,512)
        float4 v = *(const float4*)(fm + ((size_t)b * EMB + c) * HW + px0 + p4 * 4);
        sq0 += v.x * v.x; sq1 += v.y * v.y; sq2 += v.z * v.z; sq3 += v.w * v.w;
#pragma unroll
        for (int i = 0; i < 4; ++i) {
            int p = p4 * 4 + i;
            float val = (i == 0) ? v.x : (i == 1) ? v.y : (i == 2) ? v.z : v.w;
            int slot = (c >> 3) ^ ((p >> 2) & 63);
            *(_Float16*)(tile + p * 1024 + slot * 16 + (c & 7) * 2) = (_Float16)val;
        }
    }
    xnpart[(t >> 5) * 128 + p4 * 4 + 0] = sq0;
    xnpart[(t >> 5) * 128 + p4 * 4 + 1] = sq1;
    xnpart[(t >> 5) * 128 + p4 * 4 + 2] = sq2;
    xnpart[(t >> 5) * 128 + p4 * 4 + 3] = sq3;
    __syncthreads();

    if (t < 128) {
        float s = 0.f;
#pragma unroll
        for (int g = 0; g < 32; ++g) s += xnpart[g * 128 + t];
        xn[b * HW + px0 + t] = s;
    }
    const int wid = t >> 6, lane = t & 63;
#pragma unroll
    for (int rr = 0; rr < 8; ++rr) {
        int p = wid * 8 + rr;
        int phys = lane ^ ((p >> 2) & 63);
        f16x8 v = *(const f16x8*)(tile + p * 1024 + phys * 16);
        *(f16x8*)(Xh + ((size_t)b * HW + px0 + p) * EMB + lane * 8) = v;
    }
}

// ================= pA v5: m97-shape 128k x 128px, 4 waves, 2-buf dbuf, 4 blocks/CU =========
// grid = 512 px-tiles x 8 slices (slice-inner). 256 thr = 4 waves (2 kw x 2 pw);
// wave = 64k x 64px, acc[4][4] f32x4 (64 acc regs). LDS: 2 bufs x 16 KB + pn = 32.8 KB ->
// 4 blocks/CU; the per-step __syncthreads vmcnt-drain is hidden by the other 3 blocks
// (m97/m114 mechanism). Swizzle: 16B slot = cg ^ ((row>>1)&3), measured conflict-free (r8);
// inverse pre-applied on the global_load_lds source.
__global__ __launch_bounds__(256, 4)
void pA_gemm(const _Float16* __restrict__ Xh, const _Float16* __restrict__ Ph,
             const float* __restrict__ pnorm, const float* __restrict__ xn,
             _Float16* __restrict__ e_out, float4* __restrict__ pstat) {
    __shared__ __align__(16) unsigned char smem[33280];   // 2 x 16KB bufs + 512B pn
    float* pn = (float*)(smem + 32768);        // 128 f32, live whole kernel
    // epilogue aliases into dead buf region:
    float* redsum = (float*)(smem);            // [2 kw][128 px]
    float* argv_  = (float*)(smem + 1024);     // [2 kw][128 px]
    int*   argk_  = (int*)(smem + 2048);

    const int t    = threadIdx.x;
    const int lane = t & 63, wid = t >> 6;
    const int kw   = wid >> 1, pw = wid & 1;   // 2 kw x 2 pw
    const int lrow = lane >> 4, lcol = lane & 15;

    const int pt    = blockIdx.x >> 3, slice = blockIdx.x & 7;   // slice-inner
    const int gpx0  = pt * 128;
    const int k0g   = slice * 128;

    if (t < 128) pn[t] = pnorm[k0g + t];

    f32x4 acc[4][4];
#pragma unroll
    for (int i = 0; i < 4; ++i)
#pragma unroll
        for (int j = 0; j < 4; ++j)
#pragma unroll
            for (int e = 0; e < 4; ++e) acc[i][j][e] = 0.0f;

    // staging: 256 thr x 2 passes cover 128 rows x 4 slots for A, same for B.
    // row = p*64 + (t>>2), slot = t&3; LDS dest (wave-uniform base, HW adds lane*16):
    //   A: buf*16384 + p*4096 + wid*1024 ; B: +8192.
    // source cg = slot ^ ((row>>1)&3)  (involution; ds_read applies the same).
    const int srow = t >> 2, sslot = t & 3;
    auto stage = [&](int buf, int ks) {
        const int c0 = ks * 32;
#pragma unroll
        for (int p = 0; p < 2; ++p) {
            int row = p * 64 + srow;
            int cg  = sslot ^ ((row >> 1) & 3);
            __builtin_amdgcn_global_load_lds(
                (const __attribute__((address_space(1))) void*)(Ph + (size_t)(k0g + row) * EMB + c0 + cg * 8),
                (__attribute__((address_space(3))) void*)(smem + buf * 16384 + p * 4096 + wid * 1024),
                16, 0, 0);
            __builtin_amdgcn_global_load_lds(
                (const __attribute__((address_space(1))) void*)(Xh + (size_t)(gpx0 + row) * EMB + c0 + cg * 8),
                (__attribute__((address_space(3))) void*)(smem + buf * 16384 + 8192 + p * 4096 + wid * 1024),
                16, 0, 0);
        }
    };

    stage(0, 0);
    __syncthreads();

#pragma unroll
    for (int ks = 0; ks < 16; ++ks) {
        const unsigned char* cb = smem + (ks & 1) * 16384;
        if (ks < 15) stage((ks & 1) ^ 1, ks + 1);   // prefetch next tile (WAR safe: other buf)

        f16x8 bf[4];
#pragma unroll
        for (int nf = 0; nf < 4; ++nf) {
            int px = pw * 64 + nf * 16 + lcol;
            bf[nf] = *(const f16x8*)(cb + 8192 + px * 64 + ((lrow ^ ((px >> 1) & 3)) << 4));
        }
        __builtin_amdgcn_s_setprio(1);
#pragma unroll
        for (int mf = 0; mf < 4; ++mf) {
            int r = kw * 64 + mf * 16 + lcol;
            f16x8 af = *(const f16x8*)(cb + r * 64 + ((lrow ^ ((r >> 1) & 3)) << 4));
#pragma unroll
            for (int nf = 0; nf < 4; ++nf)
                acc[mf][nf] = __builtin_amdgcn_mfma_f32_16x16x32_f16(af, bf[nf], acc[mf][nf], 0, 0, 0);
        }
        __builtin_amdgcn_s_setprio(0);
        __syncthreads();   // drains vmcnt; next buf staged; overlap comes from 4 blocks/CU
    }

    // ---- logits; per-(kw) slice-partial max/argmax ----
    float xnv[4];
#pragma unroll
    for (int nf = 0; nf < 4; ++nf) xnv[nf] = xn[gpx0 + pw * 64 + nf * 16 + lcol];

    float lav[4] = {-1e30f, -1e30f, -1e30f, -1e30f};
    int   lak[4] = {0, 0, 0, 0};
#pragma unroll
    for (int mf = 0; mf < 4; ++mf) {
        const int klb = kw * 64 + mf * 16 + lrow * 4;
        float4 pn4 = *(const float4*)(pn + klb);
#pragma unroll
        for (int nf = 0; nf < 4; ++nf)
#pragma unroll
            for (int j = 0; j < 4; ++j) {
                float pnj = (j == 0) ? pn4.x : (j == 1) ? pn4.y : (j == 2) ? pn4.z : pn4.w;
                float d2 = fmaxf(xnv[nf] + pnj - 2.0f * acc[mf][nf][j], 0.0f);
                float sq;
                asm("v_sqrt_f32 %0, %1" : "=v"(sq) : "v"(d2));
                float lg = -INV_TEMP * sq;
                acc[mf][nf][j] = lg;
                if (lg > lav[nf]) { lav[nf] = lg; lak[nf] = klb + j; }   // ascending k, strict >
            }
    }
#pragma unroll
    for (int nf = 0; nf < 4; ++nf)
#pragma unroll
        for (int m = 16; m <= 32; m <<= 1) {
            float ov = __shfl_xor(lav[nf], m);
            int   ok = __shfl_xor(lak[nf], m);
            if (ov > lav[nf] || (ov == lav[nf] && ok < lak[nf])) { lav[nf] = ov; lak[nf] = ok; }
        }
    if (lane < 16)
#pragma unroll
        for (int nf = 0; nf < 4; ++nf) {
            int px = pw * 64 + nf * 16 + lane;
            argv_[kw * 128 + px] = lav[nf];
            argk_[kw * 128 + px] = lak[nf];
        }
    __syncthreads();

    // ---- slice max per px (max of 2 kw argmax values); e = exp(lg - m); partial sums ----
#pragma unroll
    for (int nf = 0; nf < 4; ++nf) {
        int px = pw * 64 + nf * 16 + lcol;
        float m = fmaxf(argv_[px], argv_[128 + px]);
        float s = 0.0f;
#pragma unroll
        for (int mf = 0; mf < 4; ++mf)
#pragma unroll
            for (int j = 0; j < 4; ++j) {
                float e = __expf(acc[mf][nf][j] - m);
                acc[mf][nf][j] = e;
                s += e;
            }
        s += __shfl_xor(s, 16);
        s += __shfl_xor(s, 32);
        if (lane < 16) redsum[kw * 128 + nf * 16 + pw * 64 + lane] = s;
    }

    // ---- write e (fp16) px-contiguous: e[gpx][k0g + kl] ----
#pragma unroll
    for (int mf = 0; mf < 4; ++mf)
#pragma unroll
        for (int nf = 0; nf < 4; ++nf) {
            int px = pw * 64 + nf * 16 + lcol;
            int kl = kw * 64 + mf * 16 + lrow * 4;
            f16x4 h;
#pragma unroll
            for (int j = 0; j < 4; ++j) h[j] = (_Float16)acc[mf][nf][j];
            *(f16x4*)(e_out + (size_t)(gpx0 + px) * NPROTO + k0g + kl) = h;
        }
    __syncthreads();

    // ---- per-px slice stats: {pmax, psum, argmax k (global)} ----
    if (kw == 0 && lane < 16) {
#pragma unroll
        for (int nf = 0; nf < 4; ++nf) {
            int px = pw * 64 + nf * 16 + lane;
            float av = argv_[px]; int ak = argk_[px];
            float a1 = argv_[128 + px]; int k1 = argk_[128 + px];
            if (a1 > av) { av = a1; ak = k1; }      // kw0 first -> ties keep smaller k
            float s = redsum[px] + redsum[128 + px];
            float4 st;
            st.x = av; st.y = s; st.z = __int_as_float(k0g + ak); st.w = 0.0f;
            pstat[(size_t)slice * NPIX + gpx0 + px] = st;
        }
    }
}

// ================= pC: combine 8 slice stats -> per-slice scale, argmax counts =============
__global__ void pC_combine(const float4* __restrict__ pstat, float* __restrict__ scale,
                           int* __restrict__ counts) {
    int px = blockIdx.x * 256 + threadIdx.x;
    if (px >= NPIX) return;
    float4 st[NSLICE];
#pragma unroll
    for (int s = 0; s < NSLICE; ++s) st[s] = pstat[(size_t)s * NPIX + px];
    float m = -1e30f;
#pragma unroll
    for (int s = 0; s < NSLICE; ++s) m = fmaxf(m, st[s].x);
    float es[NSLICE];
    float S = 0.0f;
#pragma unroll
    for (int s = 0; s < NSLICE; ++s) { es[s] = __expf(st[s].x - m); S += st[s].y * es[s]; }
    float rs = 1.0f / S;
#pragma unroll
    for (int s = 0; s < NSLICE; ++s) scale[(size_t)px * NSLICE + s] = es[s] * rs;
    float bv = st[0].x; int bk = __float_as_int(st[0].z);
#pragma unroll
    for (int s = 1; s < NSLICE; ++s)
        if (st[s].x > bv) { bv = st[s].x; bk = __float_as_int(st[s].z); }   // ascending k slices
    int b = px >> 12;
    atomicAdd(&counts[b * NPROTO + bk], 1);
}

// ================= pB: transpose+scale stream: out[b][k][px] = e[px][k] * scale ============
__global__ __launch_bounds__(1024)
void pB_emit(const _Float16* __restrict__ e, const float* __restrict__ scale,
             float* __restrict__ out) {
    __shared__ float tile[64 * 261];            // [k][px], pad -> mild conflicts only

    const int t = threadIdx.x;
    const int px0g = blockIdx.x * 256;
    const int b = px0g >> 12, hw0 = px0g & 4095;
    const int lpx = t >> 2, kq = t & 3;         // load: 256 px x 4 k-quads (16 f16 each)
    const int orow = t >> 4, oseg = t & 15;     // store: 64 rows x 16 segs

    for (int kc = 0; kc < 16; ++kc) {
        int slice = kc >> 1;                    // 64-k chunk -> 128-k slice
        float sc = scale[(size_t)(px0g + lpx) * NSLICE + slice];
        const _Float16* src = e + (size_t)(px0g + lpx) * NPROTO + kc * 64 + kq * 16;
        f16x8 h0 = *(const f16x8*)(src);
        f16x8 h1 = *(const f16x8*)(src + 8);
        if (kc) __syncthreads();                 // prev chunk's readers done
#pragma unroll
        for (int j = 0; j < 8; ++j) {
            tile[(kq * 16 + j) * 261 + lpx]     = (float)h0[j] * sc;
            tile[(kq * 16 + 8 + j) * 261 + lpx] = (float)h1[j] * sc;
        }
        __syncthreads();
        size_t obase = (size_t)b * NPROTO * HW + (size_t)(kc * 64 + orow) * HW + hw0 + oseg * 16;
#pragma unroll
        for (int i = 0; i < 4; ++i) {
            float4 v;
            v.x = tile[orow * 261 + oseg * 16 + i * 4 + 0];
            v.y = tile[orow * 261 + oseg * 16 + i * 4 + 1];
            v.z = tile[orow * 261 + oseg * 16 + i * 4 + 2];
            v.w = tile[orow * 261 + oseg * 16 + i * 4 + 3];
            *(float4*)(out + obase + i * 4) = v;
        }
    }
}

// ---------------- finalize: mask = (counts > 3).sum() / 16 ----------------
__global__ void finalize(const int* __restrict__ counts, float* __restrict__ out) {
    int t = threadIdx.x;  // 256
    int local = 0;
    for (int i = t; i < NB * NPROTO; i += 256) local += (counts[i] > 3) ? 1 : 0;
#pragma unroll
    for (int m = 1; m < 64; m <<= 1) local += __shfl_xor(local, m);
    __shared__ int wsum[4];
    if ((t & 63) == 0) wsum[t >> 6] = local;
    __syncthreads();
    if (t == 0) out[(size_t)NPIX * NPROTO] = (float)(wsum[0] + wsum[1] + wsum[2] + wsum[3]) / 16.0f;
}

// ================= fallback (validated round-3 fused kernel, used if ws too small) ========
__global__ __launch_bounds__(1024, 1)
void assign_fused(const float* __restrict__ fm, const _Float16* __restrict__ Ph,
                  const float* __restrict__ pnorm, int* __restrict__ counts,
                  float* __restrict__ out) {
    __shared__ __align__(16) unsigned char smem[143360];
    unsigned char* Abuf = smem;
    unsigned char* Bbuf = smem + 131072;
    float* pn           = (float*)(smem + 139264);
    float* redmax = (float*)(smem);
    float* redsum = (float*)(smem + 4096);
    float* argv_  = (float*)(smem + 8192);
    int*   argk_  = (int*)  (smem + 12288);
    float* xnsum  = (float*)(smem + 16384);
    float* xn     = (float*)(smem + 20480);

    const int t    = threadIdx.x;
    const int lane = t & 63, wid = t >> 6;
    const int lrow = lane >> 4, lcol = lane & 15;
    const int n0  = blockIdx.x * 64;
    const int b   = n0 >> 12;
    const int hw0 = n0 & 4095;

    pn[t] = pnorm[t];
    f32x4 acc[4][4];
#pragma unroll
    for (int i = 0; i < 4; ++i)
#pragma unroll
        for (int j = 0; j < 4; ++j)
#pragma unroll
            for (int e = 0; e < 4; ++e) acc[i][j][e] = 0.0f;

    const int bpx = t & 63;
    const int bc  = (t >> 6) << 1;
    const float* fmB = fm + (size_t)b * EMB * HW + hw0 + bpx;
    float sq = 0.0f;
    float bv0, bv1;

    auto stageA = [&](int cur, int ks) {
        const int c0 = ks * 32;
#pragma unroll
        for (int p = 0; p < 4; ++p) {
            int k  = p * 256 + wid * 16 + (lane >> 2);
            int cg = (lane & 3) ^ (k & 3);
            __builtin_amdgcn_global_load_lds(
                (const __attribute__((address_space(1))) void*)(Ph + (size_t)k * EMB + c0 + cg * 8),
                (__attribute__((address_space(3))) void*)(Abuf + cur * 65536 + p * 16384 + wid * 1024),
                16, 0, 0);
        }
    };
    auto loadB = [&](int ks) {
        const float* p0 = fmB + (size_t)(ks * 32 + bc) * HW;
        bv0 = p0[0]; bv1 = p0[HW];
    };
    auto writeB = [&](int cur) {
        sq += bv0 * bv0 + bv1 * bv1;
        f16x2 h; h[0] = (_Float16)bv0; h[1] = (_Float16)bv1;
        int slot = (bc >> 3) ^ (bpx & 3);
        *(f16x2*)(Bbuf + cur * 4096 + bpx * 64 + (slot << 4) + (bc & 7) * 2) = h;
    };

    stageA(0, 0); loadB(0); writeB(0);
    __syncthreads();
    int cur = 0;
    for (int ks = 0; ks < 16; ++ks) {
        if (ks < 15) { stageA(cur ^ 1, ks + 1); loadB(ks + 1); }
        f16x8 bf[4];
#pragma unroll
        for (int nf = 0; nf < 4; ++nf) {
            int px = nf * 16 + lcol;
            bf[nf] = *(const f16x8*)(Bbuf + cur * 4096 + px * 64 + ((lrow ^ (px & 3)) << 4));
        }
#pragma unroll
        for (int mf = 0; mf < 4; ++mf) {
            int r = wid * 64 + mf * 16 + lcol;
            f16x8 af = *(const f16x8*)(Abuf + cur * 65536 + r * 64 + ((lrow ^ (r & 3)) << 4));
#pragma unroll
            for (int nf = 0; nf < 4; ++nf)
                acc[mf][nf] = __builtin_amdgcn_mfma_f32_16x16x32_f16(af, bf[nf], acc[mf][nf], 0, 0, 0);
        }
        if (ks < 15) writeB(cur ^ 1);
        __syncthreads();
        cur ^= 1;
    }

    xnsum[(t >> 6) * 64 + bpx] = sq;
    __syncthreads();
    if (t < 64) {
        float s = 0.0f;
#pragma unroll
        for (int g = 0; g < 16; ++g) s += xnsum[g * 64 + t];
        xn[t] = s;
    }
    __syncthreads();

    float xnv[4];
#pragma unroll
    for (int nf = 0; nf < 4; ++nf) xnv[nf] = xn[nf * 16 + lcol];
    float lmax[4] = {-1e30f, -1e30f, -1e30f, -1e30f};
    float lav[4]  = {-1e30f, -1e30f, -1e30f, -1e30f};
    int   lak[4]  = {0, 0, 0, 0};
#pragma unroll
    for (int mf = 0; mf < 4; ++mf)
#pragma unroll
        for (int nf = 0; nf < 4; ++nf)
#pragma unroll
            for (int j = 0; j < 4; ++j) {
                int kidx = wid * 64 + mf * 16 + lrow * 4 + j;
                float d2 = xnv[nf] + pn[kidx] - 2.0f * acc[mf][nf][j];
                float lg = -INV_TEMP * sqrtf(fmaxf(d2, 0.0f));
                acc[mf][nf][j] = lg;
                if (lg > lav[nf]) { lav[nf] = lg; lak[nf] = kidx; }
                lmax[nf] = fmaxf(lmax[nf], lg);
            }
#pragma unroll
    for (int nf = 0; nf < 4; ++nf)
#pragma unroll
        for (int m = 16; m <= 32; m <<= 1) {
            float ov = __shfl_xor(lav[nf], m);
            int   ok = __shfl_xor(lak[nf], m);
            if (ov > lav[nf] || (ov == lav[nf] && ok < lak[nf])) { lav[nf] = ov; lak[nf] = ok; }
            lmax[nf] = fmaxf(lmax[nf], __shfl_xor(lmax[nf], m));
        }
    if (lane < 16)
#pragma unroll
        for (int nf = 0; nf < 4; ++nf) {
            int idx = wid * 64 + nf * 16 + lane;
            redmax[idx] = lmax[nf]; argv_[idx] = lav[nf]; argk_[idx] = lak[nf];
        }
    __syncthreads();

#pragma unroll
    for (int nf = 0; nf < 4; ++nf) {
        int px = nf * 16 + lcol;
        float gm = -1e30f, gav = -1e30f;
        int gak = 0;
#pragma unroll
        for (int w = 0; w < 16; ++w) {
            gm = fmaxf(gm, redmax[w * 64 + px]);
            float av = argv_[w * 64 + px];
            int   ak = argk_[w * 64 + px];
            if (av > gav || (av == gav && ak < gak)) { gav = av; gak = ak; }
        }
        if (wid == 0 && lane < 16) atomicAdd(&counts[b * NPROTO + gak], 1);
        float s = 0.0f;
#pragma unroll
        for (int mf = 0; mf < 4; ++mf)
#pragma unroll
            for (int j = 0; j < 4; ++j) {
                float e = __expf(acc[mf][nf][j] - gm);
                acc[mf][nf][j] = e;
                s += e;
            }
        s += __shfl_xor(s, 16);
        s += __shfl_xor(s, 32);
        if (lane < 16) redsum[wid * 64 + nf * 16 + lane] = s;
    }
    __syncthreads();

    const size_t obase = (size_t)b * NPROTO * HW + hw0;
#pragma unroll
    for (int nf = 0; nf < 4; ++nf) {
        int px = nf * 16 + lcol;
        float s = 0.0f;
#pragma unroll
        for (int w = 0; w < 16; ++w) s += redsum[w * 64 + px];
        float inv = 1.0f / s;
#pragma unroll
        for (int mf = 0; mf < 4; ++mf)
#pragma unroll
            for (int j = 0; j < 4; ++j) {
                int kidx = wid * 64 + mf * 16 + lrow * 4 + j;
                out[obase + (size_t)kidx * HW + px] = acc[mf][nf][j] * inv;
            }
    }
}

extern "C" void kernel_launch(void* const* d_in, const int* in_sizes, int n_in,
                              void* d_out, int out_size, void* d_ws, size_t ws_size,
                              hipStream_t stream) {
    const float* fm    = (const float*)d_in[0];   // [16][512][64][64] f32
    const float* proto = (const float*)d_in[1];   // [1][1024][512] f32
    float* out = (float*)d_out;

    char* ws = (char*)d_ws;
    // fast-path ws layout
    const size_t E_OFF  = 0;                               // 65536*1024*2 = 134217728
    const size_t XH_OFF = 134217728;                       // 65536*512*2 =  67108864
    const size_t PS_OFF = XH_OFF + 67108864;               // 8*65536*16  =   8388608
    const size_t SC_OFF = PS_OFF + 8388608;                // 65536*8*4   =   2097152
    const size_t XN_OFF = SC_OFF + 2097152;                // 65536*4     =    262144
    const size_t PH_OFF = XN_OFF + 262144;                 // 1024*512*2  =   1048576
    const size_t PN_OFF = PH_OFF + 1048576;                //                   4096
    const size_t CT_OFF = PN_OFF + 4096;                   //                  65536
    const size_t NEED   = CT_OFF + 65536;

    if (ws_size >= NEED) {
        _Float16* e     = (_Float16*)(ws + E_OFF);
        _Float16* Xh    = (_Float16*)(ws + XH_OFF);
        float4*   pstat = (float4*)(ws + PS_OFF);
        float*    scale = (float*)(ws + SC_OFF);
        float*    xn    = (float*)(ws + XN_OFF);
        _Float16* Ph    = (_Float16*)(ws + PH_OFF);
        float*    pnorm = (float*)(ws + PN_OFF);
        int*      counts= (int*)(ws + CT_OFF);

        prep_protos<<<NPROTO, 64, 0, stream>>>(proto, Ph, pnorm);
        zero_counts<<<(NB * NPROTO + 255) / 256, 256, 0, stream>>>(counts);
        p0_transpose<<<NB * 32, 1024, 0, stream>>>(fm, Xh, xn);
        pA_gemm<<<(NPIX / 128) * NSLICE, 256, 0, stream>>>(Xh, Ph, pnorm, xn, e, pstat);
        pC_combine<<<NPIX / 256, 256, 0, stream>>>(pstat, scale, counts);
        pB_emit<<<NPIX / 256, 1024, 0, stream>>>(e, scale, out);
        finalize<<<1, 256, 0, stream>>>(counts, out);
    } else {
        // fallback: validated fused path (round-3)
        _Float16* Ph    = (_Float16*)ws;
        float*    pnorm = (float*)(ws + (size_t)NPROTO * EMB * 2);
        int*      counts= (int*)(ws + (size_t)NPROTO * EMB * 2 + 4096);
        prep_protos<<<NPROTO, 64, 0, stream>>>(proto, Ph, pnorm);
        zero_counts<<<(NB * NPROTO + 255) / 256, 256, 0, stream>>>(counts);
        assign_fused<<<NPIX / 64, 1024, 0, stream>>>(fm, Ph, pnorm, counts, out);
        finalize<<<1, 256, 0, stream>>>(counts, out);
    }
}

// Round 11
// 300.624 us; speedup vs baseline: 1.2319x; 1.0964x over previous
//
#include <hip/hip_runtime.h>
#include <hip/hip_bf16.h>
#include <stdint.h>

typedef _Float16 f16x8 __attribute__((ext_vector_type(8)));
typedef _Float16 f16x4 __attribute__((ext_vector_type(4)));
typedef _Float16 f16x2 __attribute__((ext_vector_type(2)));
typedef float    f32x4 __attribute__((ext_vector_type(4)));

#define NPROTO 1024
#define EMB    512
#define NB     16
#define HW     4096           // 64*64
#define NPIX   (NB * HW)      // 65536
#define INV_TEMP 10.0f        // 1/0.1
#define NSLICE 8              // 128 k per slice

// ---------------- prep: prototypes f32 -> fp16, pnorm = |p|^2 (exact f32) ----------------
__global__ void prep_protos(const float* __restrict__ proto,
                            _Float16* __restrict__ Ph,
                            float* __restrict__ pnorm) {
    int k = blockIdx.x;          // 1024 blocks, 1 wave each
    int t = threadIdx.x;
    const float* src = proto + (size_t)k * EMB + t * 8;
    float4 v0 = ((const float4*)src)[0];
    float4 v1 = ((const float4*)src)[1];
    float sq = v0.x*v0.x + v0.y*v0.y + v0.z*v0.z + v0.w*v0.w
             + v1.x*v1.x + v1.y*v1.y + v1.z*v1.z + v1.w*v1.w;
    f16x8 h;
    h[0] = (_Float16)v0.x; h[1] = (_Float16)v0.y; h[2] = (_Float16)v0.z; h[3] = (_Float16)v0.w;
    h[4] = (_Float16)v1.x; h[5] = (_Float16)v1.y; h[6] = (_Float16)v1.z; h[7] = (_Float16)v1.w;
    *(f16x8*)(Ph + (size_t)k * EMB + t * 8) = h;
#pragma unroll
    for (int m = 1; m < 64; m <<= 1) sq += __shfl_xor(sq, m);
    if (t == 0) pnorm[k] = sq;
}

__global__ void zero_counts(int* __restrict__ counts) {
    int i = blockIdx.x * blockDim.x + threadIdx.x;
    if (i < NB * NPROTO) counts[i] = 0;
}

// ================= p0: fm [b][c][px] f32 -> Xh [b][px][c] fp16 (+ exact xn) ===============
__global__ __launch_bounds__(1024)
void p0_transpose(const float* __restrict__ fm, _Float16* __restrict__ Xh,
                  float* __restrict__ xn) {
    __shared__ __align__(16) unsigned char tile[128 * 1024];   // 128 px rows x 1KB (512 f16)
    __shared__ float xnpart[32 * 128];                         // 16 KB

    const int t   = threadIdx.x;
    const int b   = blockIdx.x >> 5;          // 32 px-tiles per image
    const int px0 = (blockIdx.x & 31) * 128;

    float sq0 = 0.f, sq1 = 0.f, sq2 = 0.f, sq3 = 0.f;
    const int p4 = t & 31;                    // fixed float4 column for this thread
#pragma unroll
    for (int j = 0; j < 16; ++j) {
        int f4 = j * 1024 + t;
        int c  = f4 >> 5;                     // [0,512)
        float4 v = *(const float4*)(fm + ((size_t)b * EMB + c) * HW + px0 + p4 * 4);
        sq0 += v.x * v.x; sq1 += v.y * v.y; sq2 += v.z * v.z; sq3 += v.w * v.w;
#pragma unroll
        for (int i = 0; i < 4; ++i) {
            int p = p4 * 4 + i;
            float val = (i == 0) ? v.x : (i == 1) ? v.y : (i == 2) ? v.z : v.w;
            int slot = (c >> 3) ^ ((p >> 2) & 63);
            *(_Float16*)(tile + p * 1024 + slot * 16 + (c & 7) * 2) = (_Float16)val;
        }
    }
    xnpart[(t >> 5) * 128 + p4 * 4 + 0] = sq0;
    xnpart[(t >> 5) * 128 + p4 * 4 + 1] = sq1;
    xnpart[(t >> 5) * 128 + p4 * 4 + 2] = sq2;
    xnpart[(t >> 5) * 128 + p4 * 4 + 3] = sq3;
    __syncthreads();

    if (t < 128) {
        float s = 0.f;
#pragma unroll
        for (int g = 0; g < 32; ++g) s += xnpart[g * 128 + t];
        xn[b * HW + px0 + t] = s;
    }
    const int wid = t >> 6, lane = t & 63;
#pragma unroll
    for (int rr = 0; rr < 8; ++rr) {
        int p = wid * 8 + rr;
        int phys = lane ^ ((p >> 2) & 63);
        f16x8 v = *(const f16x8*)(tile + p * 1024 + phys * 16);
        *(f16x8*)(Xh + ((size_t)b * HW + px0 + p) * EMB + lane * 8) = v;
    }
}

// ================= pA v6: m97-shape 128k x 128px + COALESCED e-write via LDS restage =======
// grid = 512 px-tiles x 8 slices (slice-inner). 256 thr = 4 waves (2 kw x 2 pw);
// wave = 64k x 64px. LDS: 2 bufs x 16 KB (K-loop) reused as EP[128px][128k] fp16 for the
// e restage; +pn/red arrays = 36.4 KB -> 4 blocks/CU. Staging uses incremental per-thread
// source pointers (+32 f16/step). Swizzles: K-loop slot = cg ^ ((row>>1)&3) (r8-verified
// conflict-free); EP slot = (kl>>2) ^ (px&31) (bijective per row).
__global__ __launch_bounds__(256, 4)
void pA_gemm(const _Float16* __restrict__ Xh, const _Float16* __restrict__ Ph,
             const float* __restrict__ pnorm, const float* __restrict__ xn,
             _Float16* __restrict__ e_out, float4* __restrict__ pstat) {
    __shared__ __align__(16) unsigned char smem[36352];
    float* pn     = (float*)(smem + 32768);    // 128 f32
    float* redsum = (float*)(smem + 33280);    // [2 kw][128 px]
    float* argv_  = (float*)(smem + 34304);    // [2 kw][128 px]
    int*   argk_  = (int*)(smem + 35328);

    const int t    = threadIdx.x;
    const int lane = t & 63, wid = t >> 6;
    const int kw   = wid >> 1, pw = wid & 1;   // 2 kw x 2 pw
    const int lrow = lane >> 4, lcol = lane & 15;

    const int pt    = blockIdx.x >> 3, slice = blockIdx.x & 7;   // slice-inner
    const int gpx0  = pt * 128;
    const int k0g   = slice * 128;

    if (t < 128) pn[t] = pnorm[k0g + t];

    f32x4 acc[4][4];
#pragma unroll
    for (int i = 0; i < 4; ++i)
#pragma unroll
        for (int j = 0; j < 4; ++j)
#pragma unroll
            for (int e = 0; e < 4; ++e) acc[i][j][e] = 0.0f;

    // staging: 256 thr x 2 passes cover 128 rows x 4 slots for A and B.
    // Incremental source pointers: advance +32 f16 (64 B) per K-step.
    const int srow = t >> 2, sslot = t & 3;
    const int scg  = sslot ^ ((srow >> 1) & 3);          // same for row and row+64
    const _Float16* pA0 = Ph + (size_t)(k0g + srow) * EMB + scg * 8;
    const _Float16* pA1 = Ph + (size_t)(k0g + 64 + srow) * EMB + scg * 8;
    const _Float16* pB0 = Xh + (size_t)(gpx0 + srow) * EMB + scg * 8;
    const _Float16* pB1 = Xh + (size_t)(gpx0 + 64 + srow) * EMB + scg * 8;

    auto stage = [&](int buf) {
        unsigned char* base = smem + buf * 16384;
        __builtin_amdgcn_global_load_lds(
            (const __attribute__((address_space(1))) void*)pA0,
            (__attribute__((address_space(3))) void*)(base + wid * 1024), 16, 0, 0);
        __builtin_amdgcn_global_load_lds(
            (const __attribute__((address_space(1))) void*)pB0,
            (__attribute__((address_space(3))) void*)(base + 8192 + wid * 1024), 16, 0, 0);
        __builtin_amdgcn_global_load_lds(
            (const __attribute__((address_space(1))) void*)pA1,
            (__attribute__((address_space(3))) void*)(base + 4096 + wid * 1024), 16, 0, 0);
        __builtin_amdgcn_global_load_lds(
            (const __attribute__((address_space(1))) void*)pB1,
            (__attribute__((address_space(3))) void*)(base + 12288 + wid * 1024), 16, 0, 0);
    };

    stage(0);
    pA0 += 32; pA1 += 32; pB0 += 32; pB1 += 32;
    __syncthreads();

#pragma unroll
    for (int ks = 0; ks < 16; ++ks) {
        const unsigned char* cb = smem + (ks & 1) * 16384;
        if (ks < 15) {
            stage((ks & 1) ^ 1);            // prefetch next tile (other buf, WAR safe)
            pA0 += 32; pA1 += 32; pB0 += 32; pB1 += 32;
        }

        f16x8 bf[4];
#pragma unroll
        for (int nf = 0; nf < 4; ++nf) {
            int px = pw * 64 + nf * 16 + lcol;
            bf[nf] = *(const f16x8*)(cb + 8192 + px * 64 + ((lrow ^ ((px >> 1) & 3)) << 4));
        }
        __builtin_amdgcn_s_setprio(1);
#pragma unroll
        for (int mf = 0; mf < 4; ++mf) {
            int r = kw * 64 + mf * 16 + lcol;
            f16x8 af = *(const f16x8*)(cb + r * 64 + ((lrow ^ ((r >> 1) & 3)) << 4));
#pragma unroll
            for (int nf = 0; nf < 4; ++nf)
                acc[mf][nf] = __builtin_amdgcn_mfma_f32_16x16x32_f16(af, bf[nf], acc[mf][nf], 0, 0, 0);
        }
        __builtin_amdgcn_s_setprio(0);
        __syncthreads();   // drains vmcnt; overlap comes from 4 blocks/CU
    }

    // ---- logits; per-(kw) slice-partial max/argmax ----
    float xnv[4];
#pragma unroll
    for (int nf = 0; nf < 4; ++nf) xnv[nf] = xn[gpx0 + pw * 64 + nf * 16 + lcol];

    float lav[4] = {-1e30f, -1e30f, -1e30f, -1e30f};
    int   lak[4] = {0, 0, 0, 0};
#pragma unroll
    for (int mf = 0; mf < 4; ++mf) {
        const int klb = kw * 64 + mf * 16 + lrow * 4;
        float4 pn4 = *(const float4*)(pn + klb);
#pragma unroll
        for (int nf = 0; nf < 4; ++nf)
#pragma unroll
            for (int j = 0; j < 4; ++j) {
                float pnj = (j == 0) ? pn4.x : (j == 1) ? pn4.y : (j == 2) ? pn4.z : pn4.w;
                float d2 = fmaxf(xnv[nf] + pnj - 2.0f * acc[mf][nf][j], 0.0f);
                float sq;
                asm("v_sqrt_f32 %0, %1" : "=v"(sq) : "v"(d2));
                float lg = -INV_TEMP * sq;
                acc[mf][nf][j] = lg;
                if (lg > lav[nf]) { lav[nf] = lg; lak[nf] = klb + j; }   // ascending k, strict >
            }
    }
#pragma unroll
    for (int nf = 0; nf < 4; ++nf)
#pragma unroll
        for (int m = 16; m <= 32; m <<= 1) {
            float ov = __shfl_xor(lav[nf], m);
            int   ok = __shfl_xor(lak[nf], m);
            if (ov > lav[nf] || (ov == lav[nf] && ok < lak[nf])) { lav[nf] = ov; lak[nf] = ok; }
        }
    if (lane < 16)
#pragma unroll
        for (int nf = 0; nf < 4; ++nf) {
            int px = pw * 64 + nf * 16 + lane;
            argv_[kw * 128 + px] = lav[nf];
            argk_[kw * 128 + px] = lak[nf];
        }
    __syncthreads();

    // ---- slice max per px; e = exp(lg - m); partial sums; EP restage (coalesced) ----
#pragma unroll
    for (int nf = 0; nf < 4; ++nf) {
        int px = pw * 64 + nf * 16 + lcol;
        float m = fmaxf(argv_[px], argv_[128 + px]);
        float s = 0.0f;
#pragma unroll
        for (int mf = 0; mf < 4; ++mf) {
            int kl = kw * 64 + mf * 16 + lrow * 4;
            f16x4 h;
#pragma unroll
            for (int j = 0; j < 4; ++j) {
                float e = __expf(acc[mf][nf][j] - m);
                s += e;
                h[j] = (_Float16)e;
            }
            int slot = (kl >> 2) ^ (px & 31);
            *(f16x4*)(smem + px * 256 + slot * 8) = h;   // EP aliases the dead K-loop bufs
        }
        s += __shfl_xor(s, 16);
        s += __shfl_xor(s, 32);
        if (lane < 16) redsum[kw * 128 + nf * 16 + pw * 64 + lane] = s;
    }
    __syncthreads();

    // ---- stream EP -> e_out: 8 lanes per px, f16x8 stores = contiguous 128 B runs ----
    {
        const int pxr = lane >> 3;           // 0..7
        const int k8  = (lane & 7) * 8;      // 0..56
#pragma unroll
        for (int it = 0; it < 4; ++it) {
            int px = wid * 32 + it * 8 + pxr;
#pragma unroll
            for (int kh = 0; kh < 2; ++kh) {
                int k0 = kh * 64 + k8;
                int s0 = ((k0 >> 2)     ) ^ (px & 31);
                int s1 = ((k0 >> 2) + 1 ) ^ (px & 31);
                f16x4 lo = *(const f16x4*)(smem + px * 256 + s0 * 8);
                f16x4 hi = *(const f16x4*)(smem + px * 256 + s1 * 8);
                f16x8 v;
                v[0] = lo[0]; v[1] = lo[1]; v[2] = lo[2]; v[3] = lo[3];
                v[4] = hi[0]; v[5] = hi[1]; v[6] = hi[2]; v[7] = hi[3];
                *(f16x8*)(e_out + (size_t)(gpx0 + px) * NPROTO + k0g + k0) = v;
            }
        }
    }

    // ---- per-px slice stats: {pmax, psum, argmax k (global)} ----
    if (kw == 0 && lane < 16) {
#pragma unroll
        for (int nf = 0; nf < 4; ++nf) {
            int px = pw * 64 + nf * 16 + lane;
            float av = argv_[px]; int ak = argk_[px];
            float a1 = argv_[128 + px]; int k1 = argk_[128 + px];
            if (a1 > av) { av = a1; ak = k1; }      // kw0 first -> ties keep smaller k
            float s = redsum[px] + redsum[128 + px];
            float4 st;
            st.x = av; st.y = s; st.z = __int_as_float(k0g + ak); st.w = 0.0f;
            pstat[(size_t)slice * NPIX + gpx0 + px] = st;
        }
    }
}

// ================= pC: combine 8 slice stats -> per-slice scale, argmax counts =============
__global__ void pC_combine(const float4* __restrict__ pstat, float* __restrict__ scale,
                           int* __restrict__ counts) {
    int px = blockIdx.x * 256 + threadIdx.x;
    if (px >= NPIX) return;
    float4 st[NSLICE];
#pragma unroll
    for (int s = 0; s < NSLICE; ++s) st[s] = pstat[(size_t)s * NPIX + px];
    float m = -1e30f;
#pragma unroll
    for (int s = 0; s < NSLICE; ++s) m = fmaxf(m, st[s].x);
    float es[NSLICE];
    float S = 0.0f;
#pragma unroll
    for (int s = 0; s < NSLICE; ++s) { es[s] = __expf(st[s].x - m); S += st[s].y * es[s]; }
    float rs = 1.0f / S;
#pragma unroll
    for (int s = 0; s < NSLICE; ++s) scale[(size_t)px * NSLICE + s] = es[s] * rs;
    float bv = st[0].x; int bk = __float_as_int(st[0].z);
#pragma unroll
    for (int s = 1; s < NSLICE; ++s)
        if (st[s].x > bv) { bv = st[s].x; bk = __float_as_int(st[s].z); }   // ascending k slices
    int b = px >> 12;
    atomicAdd(&counts[b * NPROTO + bk], 1);
}

// ================= pB: transpose+scale stream: out[b][k][px] = e[px][k] * scale ============
__global__ __launch_bounds__(1024)
void pB_emit(const _Float16* __restrict__ e, const float* __restrict__ scale,
             float* __restrict__ out) {
    __shared__ float tile[64 * 261];            // [k][px], pad -> mild conflicts only

    const int t = threadIdx.x;
    const int px0g = blockIdx.x * 256;
    const int b = px0g >> 12, hw0 = px0g & 4095;
    const int lpx = t >> 2, kq = t & 3;         // load: 256 px x 4 k-quads (16 f16 each)
    const int orow = t >> 4, oseg = t & 15;     // store: 64 rows x 16 segs

    for (int kc = 0; kc < 16; ++kc) {
        int slice = kc >> 1;                    // 64-k chunk -> 128-k slice
        float sc = scale[(size_t)(px0g + lpx) * NSLICE + slice];
        const _Float16* src = e + (size_t)(px0g + lpx) * NPROTO + kc * 64 + kq * 16;
        f16x8 h0 = *(const f16x8*)(src);
        f16x8 h1 = *(const f16x8*)(src + 8);
        if (kc) __syncthreads();                 // prev chunk's readers done
#pragma unroll
        for (int j = 0; j < 8; ++j) {
            tile[(kq * 16 + j) * 261 + lpx]     = (float)h0[j] * sc;
            tile[(kq * 16 + 8 + j) * 261 + lpx] = (float)h1[j] * sc;
        }
        __syncthreads();
        size_t obase = (size_t)b * NPROTO * HW + (size_t)(kc * 64 + orow) * HW + hw0 + oseg * 16;
#pragma unroll
        for (int i = 0; i < 4; ++i) {
            float4 v;
            v.x = tile[orow * 261 + oseg * 16 + i * 4 + 0];
            v.y = tile[orow * 261 + oseg * 16 + i * 4 + 1];
            v.z = tile[orow * 261 + oseg * 16 + i * 4 + 2];
            v.w = tile[orow * 261 + oseg * 16 + i * 4 + 3];
            *(float4*)(out + obase + i * 4) = v;
        }
    }
}

// ---------------- finalize: mask = (counts > 3).sum() / 16 ----------------
__global__ void finalize(const int* __restrict__ counts, float* __restrict__ out) {
    int t = threadIdx.x;  // 256
    int local = 0;
    for (int i = t; i < NB * NPROTO; i += 256) local += (counts[i] > 3) ? 1 : 0;
#pragma unroll
    for (int m = 1; m < 64; m <<= 1) local += __shfl_xor(local, m);
    __shared__ int wsum[4];
    if ((t & 63) == 0) wsum[t >> 6] = local;
    __syncthreads();
    if (t == 0) out[(size_t)NPIX * NPROTO] = (float)(wsum[0] + wsum[1] + wsum[2] + wsum[3]) / 16.0f;
}

// ================= fallback (validated round-3 fused kernel, used if ws too small) ========
__global__ __launch_bounds__(1024, 1)
void assign_fused(const float* __restrict__ fm, const _Float16* __restrict__ Ph,
                  const float* __restrict__ pnorm, int* __restrict__ counts,
                  float* __restrict__ out) {
    __shared__ __align__(16) unsigned char smem[143360];
    unsigned char* Abuf = smem;
    unsigned char* Bbuf = smem + 131072;
    float* pn           = (float*)(smem + 139264);
    float* redmax = (float*)(smem);
    float* redsum = (float*)(smem + 4096);
    float* argv_  = (float*)(smem + 8192);
    int*   argk_  = (int*)  (smem + 12288);
    float* xnsum  = (float*)(smem + 16384);
    float* xn     = (float*)(smem + 20480);

    const int t    = threadIdx.x;
    const int lane = t & 63, wid = t >> 6;
    const int lrow = lane >> 4, lcol = lane & 15;
    const int n0  = blockIdx.x * 64;
    const int b   = n0 >> 12;
    const int hw0 = n0 & 4095;

    pn[t] = pnorm[t];
    f32x4 acc[4][4];
#pragma unroll
    for (int i = 0; i < 4; ++i)
#pragma unroll
        for (int j = 0; j < 4; ++j)
#pragma unroll
            for (int e = 0; e < 4; ++e) acc[i][j][e] = 0.0f;

    const int bpx = t & 63;
    const int bc  = (t >> 6) << 1;
    const float* fmB = fm + (size_t)b * EMB * HW + hw0 + bpx;
    float sq = 0.0f;
    float bv0, bv1;

    auto stageA = [&](int cur, int ks) {
        const int c0 = ks * 32;
#pragma unroll
        for (int p = 0; p < 4; ++p) {
            int k  = p * 256 + wid * 16 + (lane >> 2);
            int cg = (lane & 3) ^ (k & 3);
            __builtin_amdgcn_global_load_lds(
                (const __attribute__((address_space(1))) void*)(Ph + (size_t)k * EMB + c0 + cg * 8),
                (__attribute__((address_space(3))) void*)(Abuf + cur * 65536 + p * 16384 + wid * 1024),
                16, 0, 0);
        }
    };
    auto loadB = [&](int ks) {
        const float* p0 = fmB + (size_t)(ks * 32 + bc) * HW;
        bv0 = p0[0]; bv1 = p0[HW];
    };
    auto writeB = [&](int cur) {
        sq += bv0 * bv0 + bv1 * bv1;
        f16x2 h; h[0] = (_Float16)bv0; h[1] = (_Float16)bv1;
        int slot = (bc >> 3) ^ (bpx & 3);
        *(f16x2*)(Bbuf + cur * 4096 + bpx * 64 + (slot << 4) + (bc & 7) * 2) = h;
    };

    stageA(0, 0); loadB(0); writeB(0);
    __syncthreads();
    int cur = 0;
    for (int ks = 0; ks < 16; ++ks) {
        if (ks < 15) { stageA(cur ^ 1, ks + 1); loadB(ks + 1); }
        f16x8 bf[4];
#pragma unroll
        for (int nf = 0; nf < 4; ++nf) {
            int px = nf * 16 + lcol;
            bf[nf] = *(const f16x8*)(Bbuf + cur * 4096 + px * 64 + ((lrow ^ (px & 3)) << 4));
        }
#pragma unroll
        for (int mf = 0; mf < 4; ++mf) {
            int r = wid * 64 + mf * 16 + lcol;
            f16x8 af = *(const f16x8*)(Abuf + cur * 65536 + r * 64 + ((lrow ^ (r & 3)) << 4));
#pragma unroll
            for (int nf = 0; nf < 4; ++nf)
                acc[mf][nf] = __builtin_amdgcn_mfma_f32_16x16x32_f16(af, bf[nf], acc[mf][nf], 0, 0, 0);
        }
        if (ks < 15) writeB(cur ^ 1);
        __syncthreads();
        cur ^= 1;
    }

    xnsum[(t >> 6) * 64 + bpx] = sq;
    __syncthreads();
    if (t < 64) {
        float s = 0.0f;
#pragma unroll
        for (int g = 0; g < 16; ++g) s += xnsum[g * 64 + t];
        xn[t] = s;
    }
    __syncthreads();

    float xnv[4];
#pragma unroll
    for (int nf = 0; nf < 4; ++nf) xnv[nf] = xn[nf * 16 + lcol];
    float lmax[4] = {-1e30f, -1e30f, -1e30f, -1e30f};
    float lav[4]  = {-1e30f, -1e30f, -1e30f, -1e30f};
    int   lak[4]  = {0, 0, 0, 0};
#pragma unroll
    for (int mf = 0; mf < 4; ++mf)
#pragma unroll
        for (int nf = 0; nf < 4; ++nf)
#pragma unroll
            for (int j = 0; j < 4; ++j) {
                int kidx = wid * 64 + mf * 16 + lrow * 4 + j;
                float d2 = xnv[nf] + pn[kidx] - 2.0f * acc[mf][nf][j];
                float lg = -INV_TEMP * sqrtf(fmaxf(d2, 0.0f));
                acc[mf][nf][j] = lg;
                if (lg > lav[nf]) { lav[nf] = lg; lak[nf] = kidx; }
                lmax[nf] = fmaxf(lmax[nf], lg);
            }
#pragma unroll
    for (int nf = 0; nf < 4; ++nf)
#pragma unroll
        for (int m = 16; m <= 32; m <<= 1) {
            float ov = __shfl_xor(lav[nf], m);
            int   ok = __shfl_xor(lak[nf], m);
            if (ov > lav[nf] || (ov == lav[nf] && ok < lak[nf])) { lav[nf] = ov; lak[nf] = ok; }
            lmax[nf] = fmaxf(lmax[nf], __shfl_xor(lmax[nf], m));
        }
    if (lane < 16)
#pragma unroll
        for (int nf = 0; nf < 4; ++nf) {
            int idx = wid * 64 + nf * 16 + lane;
            redmax[idx] = lmax[nf]; argv_[idx] = lav[nf]; argk_[idx] = lak[nf];
        }
    __syncthreads();

#pragma unroll
    for (int nf = 0; nf < 4; ++nf) {
        int px = nf * 16 + lcol;
        float gm = -1e30f, gav = -1e30f;
        int gak = 0;
#pragma unroll
        for (int w = 0; w < 16; ++w) {
            gm = fmaxf(gm, redmax[w * 64 + px]);
            float av = argv_[w * 64 + px];
            int   ak = argk_[w * 64 + px];
            if (av > gav || (av == gav && ak < gak)) { gav = av; gak = ak; }
        }
        if (wid == 0 && lane < 16) atomicAdd(&counts[b * NPROTO + gak], 1);
        float s = 0.0f;
#pragma unroll
        for (int mf = 0; mf < 4; ++mf)
#pragma unroll
            for (int j = 0; j < 4; ++j) {
                float e = __expf(acc[mf][nf][j] - gm);
                acc[mf][nf][j] = e;
                s += e;
            }
        s += __shfl_xor(s, 16);
        s += __shfl_xor(s, 32);
        if (lane < 16) redsum[wid * 64 + nf * 16 + lane] = s;
    }
    __syncthreads();

    const size_t obase = (size_t)b * NPROTO * HW + hw0;
#pragma unroll
    for (int nf = 0; nf < 4; ++nf) {
        int px = nf * 16 + lcol;
        float s = 0.0f;
#pragma unroll
        for (int w = 0; w < 16; ++w) s += redsum[w * 64 + px];
        float inv = 1.0f / s;
#pragma unroll
        for (int mf = 0; mf < 4; ++mf)
#pragma unroll
            for (int j = 0; j < 4; ++j) {
                int kidx = wid * 64 + mf * 16 + lrow * 4 + j;
                out[obase + (size_t)kidx * HW + px] = acc[mf][nf][j] * inv;
            }
    }
}

extern "C" void kernel_launch(void* const* d_in, const int* in_sizes, int n_in,
                              void* d_out, int out_size, void* d_ws, size_t ws_size,
                              hipStream_t stream) {
    const float* fm    = (const float*)d_in[0];   // [16][512][64][64] f32
    const float* proto = (const float*)d_in[1];   // [1][1024][512] f32
    float* out = (float*)d_out;

    char* ws = (char*)d_ws;
    // fast-path ws layout
    const size_t E_OFF  = 0;                               // 65536*1024*2 = 134217728
    const size_t XH_OFF = 134217728;                       // 65536*512*2 =  67108864
    const size_t PS_OFF = XH_OFF + 67108864;               // 8*65536*16  =   8388608
    const size_t SC_OFF = PS_OFF + 8388608;                // 65536*8*4   =   2097152
    const size_t XN_OFF = SC_OFF + 2097152;                // 65536*4     =    262144
    const size_t PH_OFF = XN_OFF + 262144;                 // 1024*512*2  =   1048576
    const size_t PN_OFF = PH_OFF + 1048576;                //                   4096
    const size_t CT_OFF = PN_OFF + 4096;                   //                  65536
    const size_t NEED   = CT_OFF + 65536;

    if (ws_size >= NEED) {
        _Float16* e     = (_Float16*)(ws + E_OFF);
        _Float16* Xh    = (_Float16*)(ws + XH_OFF);
        float4*   pstat = (float4*)(ws + PS_OFF);
        float*    scale = (float*)(ws + SC_OFF);
        float*    xn    = (float*)(ws + XN_OFF);
        _Float16* Ph    = (_Float16*)(ws + PH_OFF);
        float*    pnorm = (float*)(ws + PN_OFF);
        int*      counts= (int*)(ws + CT_OFF);

        prep_protos<<<NPROTO, 64, 0, stream>>>(proto, Ph, pnorm);
        zero_counts<<<(NB * NPROTO + 255) / 256, 256, 0, stream>>>(counts);
        p0_transpose<<<NB * 32, 1024, 0, stream>>>(fm, Xh, xn);
        pA_gemm<<<(NPIX / 128) * NSLICE, 256, 0, stream>>>(Xh, Ph, pnorm, xn, e, pstat);
        pC_combine<<<NPIX / 256, 256, 0, stream>>>(pstat, scale, counts);
        pB_emit<<<NPIX / 256, 1024, 0, stream>>>(e, scale, out);
        finalize<<<1, 256, 0, stream>>>(counts, out);
    } else {
        // fallback: validated fused path (round-3)
        _Float16* Ph    = (_Float16*)ws;
        float*    pnorm = (float*)(ws + (size_t)NPROTO * EMB * 2);
        int*      counts= (int*)(ws + (size_t)NPROTO * EMB * 2 + 4096);
        prep_protos<<<NPROTO, 64, 0, stream>>>(proto, Ph, pnorm);
        zero_counts<<<(NB * NPROTO + 255) / 256, 256, 0, stream>>>(counts);
        assign_fused<<<NPIX / 64, 1024, 0, stream>>>(fm, Ph, pnorm, counts, out);
        finalize<<<1, 256, 0, stream>>>(counts, out);
    }
}